// Round 16
// baseline (63.466 us; speedup 1.0000x reference)
//
#include <hip/hip_runtime.h>

typedef __attribute__((ext_vector_type(8)))  short s8v;
typedef __attribute__((ext_vector_type(4)))  short s4v;
typedef __attribute__((ext_vector_type(16))) float f16v;
typedef __attribute__((ext_vector_type(2)))  int   i2v;
typedef __attribute__((ext_vector_type(2)))  float f2v;

__device__ __forceinline__ unsigned short f2bf(float f) {
  union { float f; unsigned u; } v; v.f = f;
  unsigned r = v.u + 0x7FFFu + ((v.u >> 16) & 1u);
  return (unsigned short)(r >> 16);
}
__device__ __forceinline__ float bf2f(unsigned short b) {
  return __uint_as_float((unsigned)b << 16);
}
__device__ __forceinline__ float fexp2(float x) {
#if __has_builtin(__builtin_amdgcn_exp2f)
  return __builtin_amdgcn_exp2f(x);
#else
  return exp2f(x);
#endif
}
__device__ __forceinline__ f2v mk2(float a, float b) { f2v r; r[0] = a; r[1] = b; return r; }

// ---------------- prep bodies ----------------
__device__ __forceinline__ void gn_stats_body(
    int blk, const float* __restrict__ x, const float* __restrict__ gamma,
    const float* __restrict__ beta, float* __restrict__ ab, float* sh)
{
  int n = blk >> 5, g = blk & 31;
  int t = threadIdx.x; int cl = t >> 6, lane = t & 63;
  const float4* x4 = (const float4*)(x + (size_t)(n * 128 + g * 4 + cl) * 4096);
  float s = 0.f, ss = 0.f;
  #pragma unroll
  for (int j = 0; j < 16; ++j) {
    float4 v = x4[lane + 64 * j];
    s  += v.x + v.y + v.z + v.w;
    ss += v.x * v.x + v.y * v.y + v.z * v.z + v.w * v.w;
  }
  #pragma unroll
  for (int m = 32; m >= 1; m >>= 1) { s += __shfl_xor(s, m); ss += __shfl_xor(ss, m); }
  if (lane == 0) { sh[cl] = s; sh[4 + cl] = ss; }
  __syncthreads();
  if (t < 4) {
    float mu = (sh[0] + sh[1] + sh[2] + sh[3]) * (1.f / 16384.f);
    float e  = (sh[4] + sh[5] + sh[6] + sh[7]) * (1.f / 16384.f);
    float r  = rsqrtf(e - mu * mu + 1e-5f);
    int c = g * 4 + t;
    float al = gamma[c] * r;
    ab[n * 128 + c] = al;
    ab[1024 + n * 128 + c] = beta[c] - mu * al;
  }
}

__device__ __forceinline__ void pool_aff_body(
    int blk, const float* __restrict__ x,
    const float* __restrict__ g1, const float* __restrict__ b1,
    const float* __restrict__ g2, const float* __restrict__ b2,
    float* __restrict__ pooled, float* __restrict__ ab, float* sh)
{
  int n = blk >> 5, g = blk & 31;
  int t = threadIdx.x; int cl = t >> 6, lane = t & 63;
  int c = g * 4 + cl;
  const float* xb = x + (size_t)(n * 128 + c) * 4096;
  float* pb = pooled + (size_t)(n * 128 + c) * 1024;
  float s = 0.f, ss = 0.f;
  #pragma unroll
  for (int j = 0; j < 8; ++j) {
    int pp = (lane + 64 * j) * 2;
    int py = pp >> 5, px2 = pp & 31;
    const float* r0 = xb + py * 128 + px2 * 2;
    float4 A = *(const float4*)r0;
    float4 B = *(const float4*)(r0 + 64);
    float v0 = 0.25f * (A.x + A.y + B.x + B.y);
    float v1 = 0.25f * (A.z + A.w + B.z + B.w);
    float2 wv; wv.x = v0; wv.y = v1;
    *(float2*)(pb + pp) = wv;
    s += v0 + v1; ss += v0 * v0 + v1 * v1;
  }
  #pragma unroll
  for (int m = 32; m >= 1; m >>= 1) { s += __shfl_xor(s, m); ss += __shfl_xor(ss, m); }
  if (lane == 0) { sh[cl] = s; sh[4 + cl] = ss; }
  __syncthreads();
  if (t < 4) {
    float mu1 = (sh[0] + sh[1] + sh[2] + sh[3]) * (1.f / 4096.f);
    float e1  = (sh[4] + sh[5] + sh[6] + sh[7]) * (1.f / 4096.f);
    float r1  = rsqrtf(e1 - mu1 * mu1 + 1e-5f);
    float mzs = 0.f, e2s = 0.f;
    #pragma unroll
    for (int cc = 0; cc < 4; ++cc) {
      int ch = g * 4 + cc;
      float a = r1 * g1[ch];
      float d = b1[ch] - mu1 * a;
      float m = sh[cc] * (1.f / 1024.f);
      float q = sh[4 + cc] * (1.f / 1024.f);
      mzs += a * m + d;
      e2s += a * a * q + 2.f * a * d * m + d * d;
    }
    float mu2 = 0.25f * mzs;
    float r2  = rsqrtf(0.25f * e2s - mu2 * mu2 + 1e-5f);
    int ch = g * 4 + t;
    float a = r1 * g1[ch];
    float d = b1[ch] - mu1 * a;
    ab[n * 128 + ch] = a * r2 * g2[ch];
    ab[1024 + n * 128 + ch] = (d - mu2) * r2 * g2[ch] + b2[ch];
  }
}

__device__ __forceinline__ void wsplit_body(
    int b, const float* __restrict__ W, unsigned short* __restrict__ whi,
    unsigned short* __restrict__ wlo)
{
  int idx = b * 256 + threadIdx.x;
  #pragma unroll
  for (int k = 0; k < 4; ++k) {
    int f = idx + k * 4096;
    int o = f >> 7, c = f & 127;
    float v = W[f];
    unsigned short hb = f2bf(v);
    unsigned short lb = f2bf(v - bf2f(hb));
    int cq = c >> 2;
    int adr = (o * 16 + ((cq >> 1) ^ (o & 7))) * 8 + (cq & 1) * 4 + (c & 3);
    whi[adr] = hb; wlo[adr] = lb;
  }
}

__global__ __launch_bounds__(256) void prep_k(
    const float* __restrict__ q_src, const float* __restrict__ g_nq, const float* __restrict__ b_nq,
    const float* __restrict__ k_src, const float* __restrict__ g_srk, const float* __restrict__ b_srk,
    const float* __restrict__ g_nk, const float* __restrict__ b_nk,
    const float* __restrict__ v_src, const float* __restrict__ g_srv, const float* __restrict__ b_srv,
    const float* __restrict__ g_nv, const float* __restrict__ b_nv,
    const float* __restrict__ Wp,
    float* __restrict__ qab, float* __restrict__ kab, float* __restrict__ vab,
    float* __restrict__ knp, float* __restrict__ vnp,
    unsigned short* __restrict__ whi, unsigned short* __restrict__ wlo)
{
  __shared__ float sh[8];
  int b = blockIdx.x;
  if (b < 256) gn_stats_body(b, q_src, g_nq, b_nq, qab, sh);
  else if (b < 512) pool_aff_body(b - 256, k_src, g_srk, b_srk, g_nk, b_nk, knp, kab, sh);
  else if (b < 768) pool_aff_body(b - 512, v_src, g_srv, b_srv, g_nv, b_nv, vnp, vab, sh);
  else wsplit_body(b - 768, Wp, whi, wlo);
}

// ------- conv1x1 body with fused input affine (bf16 MFMA) -------
__device__ __forceinline__ void conv_body(
    int blk, const float* __restrict__ x, const float* __restrict__ ab,
    const float* __restrict__ W, const float* __restrict__ bias,
    unsigned short* __restrict__ po, int S, float outScale, int vt_mode,
    unsigned short* smem)
{
  unsigned short* Wsw = smem;
  unsigned short* xsw = smem + 16384;
  int t = threadIdx.x;
  int spb = S >> 7;
  int n  = blk / spb;
  int s0 = (blk % spb) << 7;

  #pragma unroll
  for (int k = 0; k < 16; ++k) {
    int f4 = t + (k << 8);
    int o = f4 >> 5, cq = f4 & 31;
    float4 wq = *(const float4*)(W + (size_t)o * 128 + cq * 4);
    union { unsigned q[2]; s4v v; } hv;
    asm("v_cvt_pk_bf16_f32 %0, %1, %2" : "=v"(hv.q[0]) : "v"(wq.x), "v"(wq.y));
    asm("v_cvt_pk_bf16_f32 %0, %1, %2" : "=v"(hv.q[1]) : "v"(wq.z), "v"(wq.w));
    *(s4v*)(Wsw + (o * 16 + ((cq >> 1) ^ (o & 7))) * 8 + (cq & 1) * 4) = hv.v;
  }
  int sl = t & 127, coh = t >> 7;
  for (int co = coh; co < 16; co += 2) {
    const float* xb = x + (size_t)(n * 128 + co * 8) * S + s0 + sl;
    const float* aa = ab + n * 128 + co * 8;
    const float* bb = aa + 1024;
    float f[8];
    #pragma unroll
    for (int e = 0; e < 8; ++e) f[e] = fmaf(xb[(size_t)e * S], aa[e], bb[e]);
    union { unsigned q[4]; s8v v; } xv;
    #pragma unroll
    for (int e = 0; e < 4; ++e)
      asm("v_cvt_pk_bf16_f32 %0, %1, %2" : "=v"(xv.q[e]) : "v"(f[2*e]), "v"(f[2*e+1]));
    *(s8v*)(xsw + (co * 128 + sl) * 8) = xv.v;
  }
  __syncthreads();

  int lane = t & 63, w = t >> 6;
  int l31 = lane & 31, h = lane >> 5;
  int wo = (w & 1) << 6, wsp = (w >> 1) << 6;
  f16v acc00 = {}, acc01 = {}, acc10 = {}, acc11 = {};
  #pragma unroll
  for (int reg = 0; reg < 16; ++reg) {
    int rm = (reg & 3) + ((reg >> 2) << 3) + (h << 2);
    float b0 = bias[wo + rm], b1 = bias[wo + 32 + rm];
    acc00[reg] = b0; acc01[reg] = b0; acc10[reg] = b1; acc11[reg] = b1;
  }
  const s8v* Wv = (const s8v*)Wsw;
  const s8v* Xv = (const s8v*)xsw;
  int o0 = wo + l31, o1 = wo + 32 + l31;
  #pragma unroll
  for (int cs = 0; cs < 8; ++cs) {
    int kk = cs * 2 + h;
    s8v a0 = Wv[o0 * 16 + (kk ^ (o0 & 7))];
    s8v a1 = Wv[o1 * 16 + (kk ^ (o1 & 7))];
    s8v b0 = Xv[kk * 128 + wsp + l31];
    s8v b1 = Xv[kk * 128 + wsp + 32 + l31];
    acc00 = __builtin_amdgcn_mfma_f32_32x32x16_bf16(a0, b0, acc00, 0, 0, 0);
    acc01 = __builtin_amdgcn_mfma_f32_32x32x16_bf16(a0, b1, acc01, 0, 0, 0);
    acc10 = __builtin_amdgcn_mfma_f32_32x32x16_bf16(a1, b0, acc10, 0, 0, 0);
    acc11 = __builtin_amdgcn_mfma_f32_32x32x16_bf16(a1, b1, acc11, 0, 0, 0);
  }
  __syncthreads();
  unsigned short* ot = smem; // [128][132]
  #pragma unroll
  for (int reg = 0; reg < 16; ++reg) {
    int rm = (reg & 3) + ((reg >> 2) << 3) + (h << 2);
    ot[(wo + rm) * 132 + wsp + l31]           = f2bf(acc00[reg] * outScale);
    ot[(wo + rm) * 132 + wsp + 32 + l31]      = f2bf(acc01[reg] * outScale);
    ot[(wo + 32 + rm) * 132 + wsp + l31]      = f2bf(acc10[reg] * outScale);
    ot[(wo + 32 + rm) * 132 + wsp + 32 + l31] = f2bf(acc11[reg] * outScale);
  }
  __syncthreads();
  if (!vt_mode) {
    unsigned* po32 = (unsigned*)po;
    int d2 = t & 15;
    for (int i = 0; i < 32; ++i) {
      int pr = (t >> 4) + (i << 4);
      int s = pr & 127, ohi_ = pr >> 7;
      unsigned lo = ot[(ohi_ * 32 + d2 * 2) * 132 + s];
      unsigned hi = ot[(ohi_ * 32 + d2 * 2 + 1) * 132 + s];
      po32[((size_t)(n * 4 + ohi_) * S + s0 + s) * 16 + d2] = lo | (hi << 16);
    }
  } else {
    unsigned* po32 = (unsigned*)po;
    const unsigned* ot32 = (const unsigned*)ot; // [128][66]
    int sp = t & 63;
    for (int i = 0; i < 32; ++i) {
      int rr = (t >> 6) + (i << 2);
      po32[((size_t)(n * 4 + (rr >> 5)) * 32 + (rr & 31)) * (S >> 1) + (s0 >> 1) + sp] =
          ot32[rr * 66 + sp];
    }
  }
}

__global__ __launch_bounds__(256) void convs_k(
    const float* __restrict__ q_src, const float* __restrict__ qab,
    const float* __restrict__ Wq, const float* __restrict__ bq, unsigned short* __restrict__ qhb,
    const float* __restrict__ knp, const float* __restrict__ kab,
    const float* __restrict__ Wk, const float* __restrict__ bk, unsigned short* __restrict__ khb,
    const float* __restrict__ vnp, const float* __restrict__ vab,
    const float* __restrict__ Wv, const float* __restrict__ bv, unsigned short* __restrict__ vtb,
    float qscale)
{
  __shared__ __align__(16) unsigned short smem[32768];
  int b = blockIdx.x;
  if (b < 256)      conv_body(b,       q_src, qab, Wq, bq, qhb, 4096, qscale, 0, smem);
  else if (b < 320) conv_body(b - 256, knp,   kab, Wk, bk, khb, 1024, 1.0f,   0, smem);
  else              conv_body(b - 320, vnp,   vab, Wv, bv, vtb, 1024, 1.0f,   1, smem);
}

// ------- fused attention + output projection (R8 structure, setprio A/B: REMOVED) -------
// Block = (n, qb: 128 q-rows). 1024 threads = 16 waves: wave (hh = w&3, qr = w>>2).
// qh: [N*4][4096][32] bf16 (pre-scaled). kh: [N*4][1024][32]. vt: [N*4][32][1024].
// whi/wlo: Wp frag images. out: [N][128][4096] f32.
__global__ __launch_bounds__(1024) void attn_proj_k(
    const unsigned short* __restrict__ qh, const unsigned short* __restrict__ kh,
    const unsigned short* __restrict__ vt, const unsigned short* __restrict__ whi,
    const unsigned short* __restrict__ wlo, const float* __restrict__ bp,
    float* __restrict__ out)
{
  __shared__ __align__(16) unsigned char SM[67584]; // 64KB KV (aliased X) + 2KB linv
  unsigned short* S16 = (unsigned short*)SM;
  float* linvp = (float*)(SM + 65536);
  int t = threadIdx.x;
  int lane = t & 63, w = t >> 6;
  int l31 = lane & 31, h = lane >> 5;
  int hh = w & 3, qr = w >> 2;
  int blk = blockIdx.x;
  int n = blk >> 5, qb = blk & 31;

  const unsigned short* qp =
      qh + (((size_t)(n * 4 + hh) * 4096 + qb * 128 + qr * 32 + l31) << 5);
  s8v qf0 = *(const s8v*)(qp + h * 8);
  s8v qf1 = *(const s8v*)(qp + (2 + h) * 8);

  // per-head staging: thread t -> head sh_=t>>8, unit si=t&255
  int sh_ = t >> 8, si = t & 255;
  size_t kvb = (size_t)(n * 4 + sh_) << 15;
  const unsigned short* kg = kh + kvb + ((si >> 2) << 5) + ((si & 3) << 3);
  const unsigned short* vg = vt + kvb + ((size_t)(si >> 3) << 10) + ((si & 7) << 3);
  int ku = (si & ~3) | ((si & 3) ^ ((si >> 3) & 3));
  int vu = (si & ~7) | ((si & 7) ^ ((si >> 3) & 7));

  // prologue: tile 0 -> buf 0
  s8v rk = *(const s8v*)kg;
  s8v rvv = *(const s8v*)vg;
  *(s8v*)(S16 + sh_ * 2048 + ku * 8) = rk;
  *(s8v*)(S16 + 16384 + sh_ * 2048 + vu * 8) = rvv;

  const f16v fz = {};
  f16v oacc = fz;
  f2v lp0 = mk2(0.f, 0.f), lp1 = mk2(0.f, 0.f);
  int kx = (l31 >> 1) & 3;
  int vx = l31 & 7;

  for (int tile = 0; tile < 16; ++tile) {
    int buf = tile & 1;
    __syncthreads();
    if (tile < 15) {
      int j = (tile + 1) << 6;
      rk = *(const s8v*)(kg + (size_t)j * 32);
      rvv = *(const s8v*)(vg + j);
    }
    const unsigned short* Kb = S16 + (buf * 4 + hh) * 2048;
    const unsigned short* Vb = S16 + 16384 + (buf * 4 + hh) * 2048;
    #pragma unroll
    for (int s = 0; s < 2; ++s) {
      int rb = s * 128 + l31 * 4;
      s8v kf0 = *(const s8v*)(Kb + ((rb + (h ^ kx)) << 3));
      s8v kf1 = *(const s8v*)(Kb + ((rb + ((2 + h) ^ kx)) << 3));
      f16v sf = __builtin_amdgcn_mfma_f32_32x32x16_bf16(kf0, qf0, fz, 0, 0, 0);
      sf = __builtin_amdgcn_mfma_f32_32x32x16_bf16(kf1, qf1, sf, 0, 0, 0);
      float p[16];
      #pragma unroll
      for (int r = 0; r < 16; ++r) p[r] = fexp2(sf[r]);
      lp0 += mk2(p[0], p[1]);  lp1 += mk2(p[2], p[3]);
      lp0 += mk2(p[4], p[5]);  lp1 += mk2(p[6], p[7]);
      lp0 += mk2(p[8], p[9]);  lp1 += mk2(p[10], p[11]);
      lp0 += mk2(p[12], p[13]); lp1 += mk2(p[14], p[15]);
      unsigned c[8];
      #pragma unroll
      for (int q = 0; q < 8; ++q)
        asm("v_cvt_pk_bf16_f32 %0, %1, %2" : "=v"(c[q]) : "v"(p[2 * q]), "v"(p[2 * q + 1]));
      i2v s02 = __builtin_amdgcn_permlane32_swap((int)c[0], (int)c[2], false, false);
      i2v s13 = __builtin_amdgcn_permlane32_swap((int)c[1], (int)c[3], false, false);
      i2v s46 = __builtin_amdgcn_permlane32_swap((int)c[4], (int)c[6], false, false);
      i2v s57 = __builtin_amdgcn_permlane32_swap((int)c[5], (int)c[7], false, false);
      union { int u[4]; s8v v; } u0, u1;
      u0.u[0] = s02[0]; u0.u[1] = s13[0]; u0.u[2] = s02[1]; u0.u[3] = s13[1];
      u1.u[0] = s46[0]; u1.u[1] = s57[0]; u1.u[2] = s46[1]; u1.u[3] = s57[1];
      s8v vf0 = *(const s8v*)(Vb + ((l31 * 8 + ((s * 4 + h) ^ vx)) << 3));
      s8v vf1 = *(const s8v*)(Vb + ((l31 * 8 + ((s * 4 + 2 + h) ^ vx)) << 3));
      oacc = __builtin_amdgcn_mfma_f32_32x32x16_bf16(u0.v, vf0, oacc, 0, 0, 0);
      oacc = __builtin_amdgcn_mfma_f32_32x32x16_bf16(u1.v, vf1, oacc, 0, 0, 0);
    }
    if (tile < 15) {
      *(s8v*)(S16 + ((buf ^ 1) * 4 + sh_) * 2048 + ku * 8) = rk;
      *(s8v*)(S16 + 16384 + ((buf ^ 1) * 4 + sh_) * 2048 + vu * 8) = rvv;
    }
  }

  // softmax denominators -> linv[head][row]
  float l_part = lp0[0] + lp0[1] + lp1[0] + lp1[1];
  float l_tot = l_part + __shfl_xor(l_part, 32);
  if (h == 0) linvp[hh * 128 + qr * 32 + l31] = 1.0f / l_tot;
  __syncthreads();  // KV reads done; linv visible; safe to alias KV region as X

  // write normalized O (hi/lo bf16) into LDS as conv B layout [ch-oct][row], XOR row^co
  unsigned short* Xh16 = S16;
  unsigned short* Xl16 = S16 + 16384;
  int ch = hh * 32 + l31, co = ch >> 3, el = ch & 7;
  #pragma unroll
  for (int reg = 0; reg < 16; ++reg) {
    int rm = (reg & 3) + ((reg >> 2) << 3) + (h << 2);
    int row = qr * 32 + rm;
    float val = oacc[reg] * linvp[hh * 128 + row];
    unsigned short hb = f2bf(val);
    unsigned short lb = f2bf(val - bf2f(hb));
    int xu = co * 128 + (row ^ co);
    Xh16[xu * 8 + el] = hb;
    Xl16[xu * 8 + el] = lb;
  }
  __syncthreads();

  // projection: wave (hh,qr) -> out channels [hh*32,+32) x spatial rows [qr*32,+32)
  int ol = hh * 32 + l31;
  const s8v* WH = (const s8v*)whi;
  const s8v* WL = (const s8v*)wlo;
  s8v ah[8], al[8];
  #pragma unroll
  for (int cs = 0; cs < 8; ++cs) {
    int kk = cs * 2 + h;
    int ia = ol * 16 + (kk ^ (ol & 7));
    ah[cs] = WH[ia];
    al[cs] = WL[ia];
  }
  f16v acc;
  #pragma unroll
  for (int reg = 0; reg < 16; ++reg) {
    int rm = (reg & 3) + ((reg >> 2) << 3) + (h << 2);
    acc[reg] = bp[hh * 32 + rm];
  }
  int srow = qr * 32 + l31;
  #pragma unroll
  for (int cs = 0; cs < 8; ++cs) {
    int kk = cs * 2 + h;
    int xu = kk * 128 + (srow ^ kk);
    s8v bh = *(const s8v*)(Xh16 + xu * 8);
    s8v bl = *(const s8v*)(Xl16 + xu * 8);
    acc = __builtin_amdgcn_mfma_f32_32x32x16_bf16(ah[cs], bh, acc, 0, 0, 0);
    acc = __builtin_amdgcn_mfma_f32_32x32x16_bf16(ah[cs], bl, acc, 0, 0, 0);
    acc = __builtin_amdgcn_mfma_f32_32x32x16_bf16(al[cs], bh, acc, 0, 0, 0);
  }
  #pragma unroll
  for (int reg = 0; reg < 16; ++reg) {
    int rm = (reg & 3) + ((reg >> 2) << 3) + (h << 2);
    out[(size_t)(n * 128 + hh * 32 + rm) * 4096 + qb * 128 + srow] = acc[reg];
  }
}

extern "C" void kernel_launch(void* const* d_in, const int* in_sizes, int n_in,
                              void* d_out, int out_size, void* d_ws, size_t ws_size,
                              hipStream_t stream)
{
  (void)in_sizes; (void)n_in; (void)out_size; (void)ws_size;
  const float* q_src = (const float*)d_in[0];
  const float* k_src = (const float*)d_in[1];
  const float* v_src = (const float*)d_in[2];
  const float* Wq = (const float*)d_in[3];
  const float* bq = (const float*)d_in[4];
  const float* Wk = (const float*)d_in[5];
  const float* bk = (const float*)d_in[6];
  const float* Wv = (const float*)d_in[7];
  const float* bv = (const float*)d_in[8];
  const float* Wp = (const float*)d_in[9];
  const float* bp = (const float*)d_in[10];
  const float* g_nq  = (const float*)d_in[11];
  const float* b_nq  = (const float*)d_in[12];
  const float* g_nk  = (const float*)d_in[13];
  const float* b_nk  = (const float*)d_in[14];
  const float* g_nv  = (const float*)d_in[15];
  const float* b_nv  = (const float*)d_in[16];
  const float* g_srk = (const float*)d_in[17];
  const float* b_srk = (const float*)d_in[18];
  const float* g_srv = (const float*)d_in[19];
  const float* b_srv = (const float*)d_in[20];

  unsigned short* qhb = (unsigned short*)d_ws;            // 8MB
  unsigned short* khb = qhb + 4194304;                    // 2MB
  unsigned short* vtb = khb + 1048576;                    // 2MB
  float* knp  = (float*)(vtb + 1048576);                  // 4MB
  float* vnp  = knp + 1048576;                            // 4MB
  float* qab  = vnp + 1048576;                            // 8KB
  float* kab  = qab + 2048;
  float* vab  = kab + 2048;
  unsigned short* whi = (unsigned short*)(vab + 2048);    // 32KB
  unsigned short* wlo = whi + 16384;

  const float QSCALE = 0.17677669529663688f * 1.44269504088896340f;

  prep_k<<<784, 256, 0, stream>>>(q_src, g_nq, b_nq,
                                  k_src, g_srk, b_srk, g_nk, b_nk,
                                  v_src, g_srv, b_srv, g_nv, b_nv,
                                  Wp, qab, kab, vab, knp, vnp, whi, wlo);
  convs_k<<<384, 256, 0, stream>>>(q_src, qab, Wq, bq, qhb,
                                   knp, kab, Wk, bk, khb,
                                   vnp, vab, Wv, bv, vtb, QSCALE);
  attn_proj_k<<<256, 1024, 0, stream>>>(qhb, khb, vtb, whi, wlo, bp, (float*)d_out);
}

// Round 17
// 62.895 us; speedup vs baseline: 1.0091x; 1.0091x over previous
//
#include <hip/hip_runtime.h>

typedef __attribute__((ext_vector_type(8)))  short s8v;
typedef __attribute__((ext_vector_type(4)))  short s4v;
typedef __attribute__((ext_vector_type(16))) float f16v;
typedef __attribute__((ext_vector_type(2)))  int   i2v;
typedef __attribute__((ext_vector_type(2)))  float f2v;

__device__ __forceinline__ unsigned short f2bf(float f) {
  union { float f; unsigned u; } v; v.f = f;
  unsigned r = v.u + 0x7FFFu + ((v.u >> 16) & 1u);
  return (unsigned short)(r >> 16);
}
__device__ __forceinline__ float bf2f(unsigned short b) {
  return __uint_as_float((unsigned)b << 16);
}
__device__ __forceinline__ float fexp2(float x) {
#if __has_builtin(__builtin_amdgcn_exp2f)
  return __builtin_amdgcn_exp2f(x);
#else
  return exp2f(x);
#endif
}
__device__ __forceinline__ f2v mk2(float a, float b) { f2v r; r[0] = a; r[1] = b; return r; }

// ---------------- prep bodies ----------------
__device__ __forceinline__ void gn_stats_body(
    int blk, const float* __restrict__ x, const float* __restrict__ gamma,
    const float* __restrict__ beta, float* __restrict__ ab, float* sh)
{
  int n = blk >> 5, g = blk & 31;
  int t = threadIdx.x; int cl = t >> 6, lane = t & 63;
  const float4* x4 = (const float4*)(x + (size_t)(n * 128 + g * 4 + cl) * 4096);
  float s = 0.f, ss = 0.f;
  #pragma unroll
  for (int j = 0; j < 16; ++j) {
    float4 v = x4[lane + 64 * j];
    s  += v.x + v.y + v.z + v.w;
    ss += v.x * v.x + v.y * v.y + v.z * v.z + v.w * v.w;
  }
  #pragma unroll
  for (int m = 32; m >= 1; m >>= 1) { s += __shfl_xor(s, m); ss += __shfl_xor(ss, m); }
  if (lane == 0) { sh[cl] = s; sh[4 + cl] = ss; }
  __syncthreads();
  if (t < 4) {
    float mu = (sh[0] + sh[1] + sh[2] + sh[3]) * (1.f / 16384.f);
    float e  = (sh[4] + sh[5] + sh[6] + sh[7]) * (1.f / 16384.f);
    float r  = rsqrtf(e - mu * mu + 1e-5f);
    int c = g * 4 + t;
    float al = gamma[c] * r;
    ab[n * 128 + c] = al;
    ab[1024 + n * 128 + c] = beta[c] - mu * al;
  }
}

__device__ __forceinline__ void pool_aff_body(
    int blk, const float* __restrict__ x,
    const float* __restrict__ g1, const float* __restrict__ b1,
    const float* __restrict__ g2, const float* __restrict__ b2,
    float* __restrict__ pooled, float* __restrict__ ab, float* sh)
{
  int n = blk >> 5, g = blk & 31;
  int t = threadIdx.x; int cl = t >> 6, lane = t & 63;
  int c = g * 4 + cl;
  const float* xb = x + (size_t)(n * 128 + c) * 4096;
  float* pb = pooled + (size_t)(n * 128 + c) * 1024;
  float s = 0.f, ss = 0.f;
  #pragma unroll
  for (int j = 0; j < 8; ++j) {
    int pp = (lane + 64 * j) * 2;
    int py = pp >> 5, px2 = pp & 31;
    const float* r0 = xb + py * 128 + px2 * 2;
    float4 A = *(const float4*)r0;
    float4 B = *(const float4*)(r0 + 64);
    float v0 = 0.25f * (A.x + A.y + B.x + B.y);
    float v1 = 0.25f * (A.z + A.w + B.z + B.w);
    float2 wv; wv.x = v0; wv.y = v1;
    *(float2*)(pb + pp) = wv;
    s += v0 + v1; ss += v0 * v0 + v1 * v1;
  }
  #pragma unroll
  for (int m = 32; m >= 1; m >>= 1) { s += __shfl_xor(s, m); ss += __shfl_xor(ss, m); }
  if (lane == 0) { sh[cl] = s; sh[4 + cl] = ss; }
  __syncthreads();
  if (t < 4) {
    float mu1 = (sh[0] + sh[1] + sh[2] + sh[3]) * (1.f / 4096.f);
    float e1  = (sh[4] + sh[5] + sh[6] + sh[7]) * (1.f / 4096.f);
    float r1  = rsqrtf(e1 - mu1 * mu1 + 1e-5f);
    float mzs = 0.f, e2s = 0.f;
    #pragma unroll
    for (int cc = 0; cc < 4; ++cc) {
      int ch = g * 4 + cc;
      float a = r1 * g1[ch];
      float d = b1[ch] - mu1 * a;
      float m = sh[cc] * (1.f / 1024.f);
      float q = sh[4 + cc] * (1.f / 1024.f);
      mzs += a * m + d;
      e2s += a * a * q + 2.f * a * d * m + d * d;
    }
    float mu2 = 0.25f * mzs;
    float r2  = rsqrtf(0.25f * e2s - mu2 * mu2 + 1e-5f);
    int ch = g * 4 + t;
    float a = r1 * g1[ch];
    float d = b1[ch] - mu1 * a;
    ab[n * 128 + ch] = a * r2 * g2[ch];
    ab[1024 + n * 128 + ch] = (d - mu2) * r2 * g2[ch] + b2[ch];
  }
}

__device__ __forceinline__ void wsplit_body(
    int b, const float* __restrict__ W, unsigned short* __restrict__ whi,
    unsigned short* __restrict__ wlo)
{
  int idx = b * 256 + threadIdx.x;
  #pragma unroll
  for (int k = 0; k < 4; ++k) {
    int f = idx + k * 4096;
    int o = f >> 7, c = f & 127;
    float v = W[f];
    unsigned short hb = f2bf(v);
    unsigned short lb = f2bf(v - bf2f(hb));
    int cq = c >> 2;
    int adr = (o * 16 + ((cq >> 1) ^ (o & 7))) * 8 + (cq & 1) * 4 + (c & 3);
    whi[adr] = hb; wlo[adr] = lb;
  }
}

__global__ __launch_bounds__(256) void prep_k(
    const float* __restrict__ q_src, const float* __restrict__ g_nq, const float* __restrict__ b_nq,
    const float* __restrict__ k_src, const float* __restrict__ g_srk, const float* __restrict__ b_srk,
    const float* __restrict__ g_nk, const float* __restrict__ b_nk,
    const float* __restrict__ v_src, const float* __restrict__ g_srv, const float* __restrict__ b_srv,
    const float* __restrict__ g_nv, const float* __restrict__ b_nv,
    const float* __restrict__ Wp,
    float* __restrict__ qab, float* __restrict__ kab, float* __restrict__ vab,
    float* __restrict__ knp, float* __restrict__ vnp,
    unsigned short* __restrict__ whi, unsigned short* __restrict__ wlo)
{
  __shared__ float sh[8];
  int b = blockIdx.x;
  if (b < 256) gn_stats_body(b, q_src, g_nq, b_nq, qab, sh);
  else if (b < 512) pool_aff_body(b - 256, k_src, g_srk, b_srk, g_nk, b_nk, knp, kab, sh);
  else if (b < 768) pool_aff_body(b - 512, v_src, g_srv, b_srv, g_nv, b_nv, vnp, vab, sh);
  else wsplit_body(b - 768, Wp, whi, wlo);
}

// ------- conv1x1 body with fused input affine (bf16 MFMA) -------
__device__ __forceinline__ void conv_body(
    int blk, const float* __restrict__ x, const float* __restrict__ ab,
    const float* __restrict__ W, const float* __restrict__ bias,
    unsigned short* __restrict__ po, int S, float outScale, int vt_mode,
    unsigned short* smem)
{
  unsigned short* Wsw = smem;
  unsigned short* xsw = smem + 16384;
  int t = threadIdx.x;
  int spb = S >> 7;
  int n  = blk / spb;
  int s0 = (blk % spb) << 7;

  #pragma unroll
  for (int k = 0; k < 16; ++k) {
    int f4 = t + (k << 8);
    int o = f4 >> 5, cq = f4 & 31;
    float4 wq = *(const float4*)(W + (size_t)o * 128 + cq * 4);
    union { unsigned q[2]; s4v v; } hv;
    asm("v_cvt_pk_bf16_f32 %0, %1, %2" : "=v"(hv.q[0]) : "v"(wq.x), "v"(wq.y));
    asm("v_cvt_pk_bf16_f32 %0, %1, %2" : "=v"(hv.q[1]) : "v"(wq.z), "v"(wq.w));
    *(s4v*)(Wsw + (o * 16 + ((cq >> 1) ^ (o & 7))) * 8 + (cq & 1) * 4) = hv.v;
  }
  int sl = t & 127, coh = t >> 7;
  for (int co = coh; co < 16; co += 2) {
    const float* xb = x + (size_t)(n * 128 + co * 8) * S + s0 + sl;
    const float* aa = ab + n * 128 + co * 8;
    const float* bb = aa + 1024;
    float f[8];
    #pragma unroll
    for (int e = 0; e < 8; ++e) f[e] = fmaf(xb[(size_t)e * S], aa[e], bb[e]);
    union { unsigned q[4]; s8v v; } xv;
    #pragma unroll
    for (int e = 0; e < 4; ++e)
      asm("v_cvt_pk_bf16_f32 %0, %1, %2" : "=v"(xv.q[e]) : "v"(f[2*e]), "v"(f[2*e+1]));
    *(s8v*)(xsw + (co * 128 + sl) * 8) = xv.v;
  }
  __syncthreads();

  int lane = t & 63, w = t >> 6;
  int l31 = lane & 31, h = lane >> 5;
  int wo = (w & 1) << 6, wsp = (w >> 1) << 6;
  f16v acc00 = {}, acc01 = {}, acc10 = {}, acc11 = {};
  #pragma unroll
  for (int reg = 0; reg < 16; ++reg) {
    int rm = (reg & 3) + ((reg >> 2) << 3) + (h << 2);
    float b0 = bias[wo + rm], b1 = bias[wo + 32 + rm];
    acc00[reg] = b0; acc01[reg] = b0; acc10[reg] = b1; acc11[reg] = b1;
  }
  const s8v* Wv = (const s8v*)Wsw;
  const s8v* Xv = (const s8v*)xsw;
  int o0 = wo + l31, o1 = wo + 32 + l31;
  #pragma unroll
  for (int cs = 0; cs < 8; ++cs) {
    int kk = cs * 2 + h;
    s8v a0 = Wv[o0 * 16 + (kk ^ (o0 & 7))];
    s8v a1 = Wv[o1 * 16 + (kk ^ (o1 & 7))];
    s8v b0 = Xv[kk * 128 + wsp + l31];
    s8v b1 = Xv[kk * 128 + wsp + 32 + l31];
    acc00 = __builtin_amdgcn_mfma_f32_32x32x16_bf16(a0, b0, acc00, 0, 0, 0);
    acc01 = __builtin_amdgcn_mfma_f32_32x32x16_bf16(a0, b1, acc01, 0, 0, 0);
    acc10 = __builtin_amdgcn_mfma_f32_32x32x16_bf16(a1, b0, acc10, 0, 0, 0);
    acc11 = __builtin_amdgcn_mfma_f32_32x32x16_bf16(a1, b1, acc11, 0, 0, 0);
  }
  __syncthreads();
  unsigned short* ot = smem; // [128][132]
  #pragma unroll
  for (int reg = 0; reg < 16; ++reg) {
    int rm = (reg & 3) + ((reg >> 2) << 3) + (h << 2);
    ot[(wo + rm) * 132 + wsp + l31]           = f2bf(acc00[reg] * outScale);
    ot[(wo + rm) * 132 + wsp + 32 + l31]      = f2bf(acc01[reg] * outScale);
    ot[(wo + 32 + rm) * 132 + wsp + l31]      = f2bf(acc10[reg] * outScale);
    ot[(wo + 32 + rm) * 132 + wsp + 32 + l31] = f2bf(acc11[reg] * outScale);
  }
  __syncthreads();
  if (!vt_mode) {
    unsigned* po32 = (unsigned*)po;
    int d2 = t & 15;
    for (int i = 0; i < 32; ++i) {
      int pr = (t >> 4) + (i << 4);
      int s = pr & 127, ohi_ = pr >> 7;
      unsigned lo = ot[(ohi_ * 32 + d2 * 2) * 132 + s];
      unsigned hi = ot[(ohi_ * 32 + d2 * 2 + 1) * 132 + s];
      po32[((size_t)(n * 4 + ohi_) * S + s0 + s) * 16 + d2] = lo | (hi << 16);
    }
  } else {
    unsigned* po32 = (unsigned*)po;
    const unsigned* ot32 = (const unsigned*)ot; // [128][66]
    int sp = t & 63;
    for (int i = 0; i < 32; ++i) {
      int rr = (t >> 6) + (i << 2);
      po32[((size_t)(n * 4 + (rr >> 5)) * 32 + (rr & 31)) * (S >> 1) + (s0 >> 1) + sp] =
          ot32[rr * 66 + sp];
    }
  }
}

__global__ __launch_bounds__(256) void convs_k(
    const float* __restrict__ q_src, const float* __restrict__ qab,
    const float* __restrict__ Wq, const float* __restrict__ bq, unsigned short* __restrict__ qhb,
    const float* __restrict__ knp, const float* __restrict__ kab,
    const float* __restrict__ Wk, const float* __restrict__ bk, unsigned short* __restrict__ khb,
    const float* __restrict__ vnp, const float* __restrict__ vab,
    const float* __restrict__ Wv, const float* __restrict__ bv, unsigned short* __restrict__ vtb,
    float qscale)
{
  __shared__ __align__(16) unsigned short smem[32768];
  int b = blockIdx.x;
  if (b < 256)      conv_body(b,       q_src, qab, Wq, bq, qhb, 4096, qscale, 0, smem);
  else if (b < 320) conv_body(b - 256, knp,   kab, Wk, bk, khb, 1024, 1.0f,   0, smem);
  else              conv_body(b - 320, vnp,   vab, Wv, bv, vtb, 1024, 1.0f,   1, smem);
}

// ------- fused attention + output projection (R15 best + XCD-chunked swizzle) -------
// Block = (n, qb: 128 q-rows). 1024 threads = 16 waves: wave (hh = w&3, qr = w>>2).
// XCD x owns image n=x entirely (256 = 8 XCDs x 32 chunked blocks) -> KV L2-resident.
// qh: [N*4][4096][32] bf16 (pre-scaled). kh: [N*4][1024][32]. vt: [N*4][32][1024].
// whi/wlo: Wp frag images. out: [N][128][4096] f32.
__global__ __launch_bounds__(1024) void attn_proj_k(
    const unsigned short* __restrict__ qh, const unsigned short* __restrict__ kh,
    const unsigned short* __restrict__ vt, const unsigned short* __restrict__ whi,
    const unsigned short* __restrict__ wlo, const float* __restrict__ bp,
    float* __restrict__ out)
{
  __shared__ __align__(16) unsigned char SM[67584]; // 64KB KV (aliased X) + 2KB linv
  unsigned short* S16 = (unsigned short*)SM;
  float* linvp = (float*)(SM + 65536);
  int t = threadIdx.x;
  int lane = t & 63, w = t >> 6;
  int l31 = lane & 31, h = lane >> 5;
  int hh = w & 3, qr = w >> 2;
  int b0 = blockIdx.x;
  int blk = (b0 & 7) * 32 + (b0 >> 3);   // bijective XCD chunking (256 = 8*32)
  int n = blk >> 5, qb = blk & 31;

  const unsigned short* qp =
      qh + (((size_t)(n * 4 + hh) * 4096 + qb * 128 + qr * 32 + l31) << 5);
  s8v qf0 = *(const s8v*)(qp + h * 8);
  s8v qf1 = *(const s8v*)(qp + (2 + h) * 8);

  // per-head staging: thread t -> head sh_=t>>8, unit si=t&255
  int sh_ = t >> 8, si = t & 255;
  size_t kvb = (size_t)(n * 4 + sh_) << 15;
  const unsigned short* kg = kh + kvb + ((si >> 2) << 5) + ((si & 3) << 3);
  const unsigned short* vg = vt + kvb + ((size_t)(si >> 3) << 10) + ((si & 7) << 3);
  int ku = (si & ~3) | ((si & 3) ^ ((si >> 3) & 3));
  int vu = (si & ~7) | ((si & 7) ^ ((si >> 3) & 7));

  // prologue: tile 0 -> buf 0
  s8v rk = *(const s8v*)kg;
  s8v rvv = *(const s8v*)vg;
  *(s8v*)(S16 + sh_ * 2048 + ku * 8) = rk;
  *(s8v*)(S16 + 16384 + sh_ * 2048 + vu * 8) = rvv;

  const f16v fz = {};
  f16v oacc = fz;
  f2v lp0 = mk2(0.f, 0.f), lp1 = mk2(0.f, 0.f);
  int kx = (l31 >> 1) & 3;
  int vx = l31 & 7;

  for (int tile = 0; tile < 16; ++tile) {
    int buf = tile & 1;
    __syncthreads();
    if (tile < 15) {
      int j = (tile + 1) << 6;
      rk = *(const s8v*)(kg + (size_t)j * 32);
      rvv = *(const s8v*)(vg + j);
    }
    const unsigned short* Kb = S16 + (buf * 4 + hh) * 2048;
    const unsigned short* Vb = S16 + 16384 + (buf * 4 + hh) * 2048;
    #pragma unroll
    for (int s = 0; s < 2; ++s) {
      int rb = s * 128 + l31 * 4;
      s8v kf0 = *(const s8v*)(Kb + ((rb + (h ^ kx)) << 3));
      s8v kf1 = *(const s8v*)(Kb + ((rb + ((2 + h) ^ kx)) << 3));
      __builtin_amdgcn_s_setprio(1);
      f16v sf = __builtin_amdgcn_mfma_f32_32x32x16_bf16(kf0, qf0, fz, 0, 0, 0);
      sf = __builtin_amdgcn_mfma_f32_32x32x16_bf16(kf1, qf1, sf, 0, 0, 0);
      __builtin_amdgcn_s_setprio(0);
      float p[16];
      #pragma unroll
      for (int r = 0; r < 16; ++r) p[r] = fexp2(sf[r]);
      lp0 += mk2(p[0], p[1]);  lp1 += mk2(p[2], p[3]);
      lp0 += mk2(p[4], p[5]);  lp1 += mk2(p[6], p[7]);
      lp0 += mk2(p[8], p[9]);  lp1 += mk2(p[10], p[11]);
      lp0 += mk2(p[12], p[13]); lp1 += mk2(p[14], p[15]);
      unsigned c[8];
      #pragma unroll
      for (int q = 0; q < 8; ++q)
        asm("v_cvt_pk_bf16_f32 %0, %1, %2" : "=v"(c[q]) : "v"(p[2 * q]), "v"(p[2 * q + 1]));
      i2v s02 = __builtin_amdgcn_permlane32_swap((int)c[0], (int)c[2], false, false);
      i2v s13 = __builtin_amdgcn_permlane32_swap((int)c[1], (int)c[3], false, false);
      i2v s46 = __builtin_amdgcn_permlane32_swap((int)c[4], (int)c[6], false, false);
      i2v s57 = __builtin_amdgcn_permlane32_swap((int)c[5], (int)c[7], false, false);
      union { int u[4]; s8v v; } u0, u1;
      u0.u[0] = s02[0]; u0.u[1] = s13[0]; u0.u[2] = s02[1]; u0.u[3] = s13[1];
      u1.u[0] = s46[0]; u1.u[1] = s57[0]; u1.u[2] = s46[1]; u1.u[3] = s57[1];
      s8v vf0 = *(const s8v*)(Vb + ((l31 * 8 + ((s * 4 + h) ^ vx)) << 3));
      s8v vf1 = *(const s8v*)(Vb + ((l31 * 8 + ((s * 4 + 2 + h) ^ vx)) << 3));
      __builtin_amdgcn_s_setprio(1);
      oacc = __builtin_amdgcn_mfma_f32_32x32x16_bf16(u0.v, vf0, oacc, 0, 0, 0);
      oacc = __builtin_amdgcn_mfma_f32_32x32x16_bf16(u1.v, vf1, oacc, 0, 0, 0);
      __builtin_amdgcn_s_setprio(0);
    }
    if (tile < 15) {
      *(s8v*)(S16 + ((buf ^ 1) * 4 + sh_) * 2048 + ku * 8) = rk;
      *(s8v*)(S16 + 16384 + ((buf ^ 1) * 4 + sh_) * 2048 + vu * 8) = rvv;
    }
  }

  // softmax denominators -> linv[head][row]
  float l_part = lp0[0] + lp0[1] + lp1[0] + lp1[1];
  float l_tot = l_part + __shfl_xor(l_part, 32);
  if (h == 0) linvp[hh * 128 + qr * 32 + l31] = 1.0f / l_tot;
  __syncthreads();  // KV reads done; linv visible; safe to alias KV region as X

  // write normalized O (hi/lo bf16) into LDS as conv B layout [ch-oct][row], XOR row^co
  unsigned short* Xh16 = S16;
  unsigned short* Xl16 = S16 + 16384;
  int ch = hh * 32 + l31, co = ch >> 3, el = ch & 7;
  #pragma unroll
  for (int reg = 0; reg < 16; ++reg) {
    int rm = (reg & 3) + ((reg >> 2) << 3) + (h << 2);
    int row = qr * 32 + rm;
    float val = oacc[reg] * linvp[hh * 128 + row];
    unsigned short hb = f2bf(val);
    unsigned short lb = f2bf(val - bf2f(hb));
    int xu = co * 128 + (row ^ co);
    Xh16[xu * 8 + el] = hb;
    Xl16[xu * 8 + el] = lb;
  }
  __syncthreads();

  // projection: wave (hh,qr) -> out channels [hh*32,+32) x spatial rows [qr*32,+32)
  int ol = hh * 32 + l31;
  const s8v* WH = (const s8v*)whi;
  const s8v* WL = (const s8v*)wlo;
  s8v ah[8], al[8];
  #pragma unroll
  for (int cs = 0; cs < 8; ++cs) {
    int kk = cs * 2 + h;
    int ia = ol * 16 + (kk ^ (ol & 7));
    ah[cs] = WH[ia];
    al[cs] = WL[ia];
  }
  f16v acc;
  #pragma unroll
  for (int reg = 0; reg < 16; ++reg) {
    int rm = (reg & 3) + ((reg >> 2) << 3) + (h << 2);
    acc[reg] = bp[hh * 32 + rm];
  }
  int srow = qr * 32 + l31;
  #pragma unroll
  for (int cs = 0; cs < 8; ++cs) {
    int kk = cs * 2 + h;
    int xu = kk * 128 + (srow ^ kk);
    s8v bh = *(const s8v*)(Xh16 + xu * 8);
    s8v bl = *(const s8v*)(Xl16 + xu * 8);
    acc = __builtin_amdgcn_mfma_f32_32x32x16_bf16(ah[cs], bh, acc, 0, 0, 0);
    acc = __builtin_amdgcn_mfma_f32_32x32x16_bf16(ah[cs], bl, acc, 0, 0, 0);
    acc = __builtin_amdgcn_mfma_f32_32x32x16_bf16(al[cs], bh, acc, 0, 0, 0);
  }
  #pragma unroll
  for (int reg = 0; reg < 16; ++reg) {
    int rm = (reg & 3) + ((reg >> 2) << 3) + (h << 2);
    out[(size_t)(n * 128 + hh * 32 + rm) * 4096 + qb * 128 + srow] = acc[reg];
  }
}

extern "C" void kernel_launch(void* const* d_in, const int* in_sizes, int n_in,
                              void* d_out, int out_size, void* d_ws, size_t ws_size,
                              hipStream_t stream)
{
  (void)in_sizes; (void)n_in; (void)out_size; (void)ws_size;
  const float* q_src = (const float*)d_in[0];
  const float* k_src = (const float*)d_in[1];
  const float* v_src = (const float*)d_in[2];
  const float* Wq = (const float*)d_in[3];
  const float* bq = (const float*)d_in[4];
  const float* Wk = (const float*)d_in[5];
  const float* bk = (const float*)d_in[6];
  const float* Wv = (const float*)d_in[7];
  const float* bv = (const float*)d_in[8];
  const float* Wp = (const float*)d_in[9];
  const float* bp = (const float*)d_in[10];
  const float* g_nq  = (const float*)d_in[11];
  const float* b_nq  = (const float*)d_in[12];
  const float* g_nk  = (const float*)d_in[13];
  const float* b_nk  = (const float*)d_in[14];
  const float* g_nv  = (const float*)d_in[15];
  const float* b_nv  = (const float*)d_in[16];
  const float* g_srk = (const float*)d_in[17];
  const float* b_srk = (const float*)d_in[18];
  const float* g_srv = (const float*)d_in[19];
  const float* b_srv = (const float*)d_in[20];

  unsigned short* qhb = (unsigned short*)d_ws;            // 8MB
  unsigned short* khb = qhb + 4194304;                    // 2MB
  unsigned short* vtb = khb + 1048576;                    // 2MB
  float* knp  = (float*)(vtb + 1048576);                  // 4MB
  float* vnp  = knp + 1048576;                            // 4MB
  float* qab  = vnp + 1048576;                            // 8KB
  float* kab  = qab + 2048;
  float* vab  = kab + 2048;
  unsigned short* whi = (unsigned short*)(vab + 2048);    // 32KB
  unsigned short* wlo = whi + 16384;

  const float QSCALE = 0.17677669529663688f * 1.44269504088896340f;

  prep_k<<<784, 256, 0, stream>>>(q_src, g_nq, b_nq,
                                  k_src, g_srk, b_srk, g_nk, b_nk,
                                  v_src, g_srv, b_srv, g_nv, b_nv,
                                  Wp, qab, kab, vab, knp, vnp, whi, wlo);
  convs_k<<<384, 256, 0, stream>>>(q_src, qab, Wq, bq, qhb,
                                   knp, kab, Wk, bk, khb,
                                   vnp, vab, Wv, bv, vtb, QSCALE);
  attn_proj_k<<<256, 1024, 0, stream>>>(qhb, khb, vtb, whi, wlo, bp, (float*)d_out);
}

// Round 18
// 62.819 us; speedup vs baseline: 1.0103x; 1.0012x over previous
//
#include <hip/hip_runtime.h>

typedef __attribute__((ext_vector_type(8)))  short s8v;
typedef __attribute__((ext_vector_type(4)))  short s4v;
typedef __attribute__((ext_vector_type(16))) float f16v;
typedef __attribute__((ext_vector_type(2)))  int   i2v;
typedef __attribute__((ext_vector_type(2)))  float f2v;

__device__ __forceinline__ unsigned short f2bf(float f) {
  union { float f; unsigned u; } v; v.f = f;
  unsigned r = v.u + 0x7FFFu + ((v.u >> 16) & 1u);
  return (unsigned short)(r >> 16);
}
__device__ __forceinline__ float bf2f(unsigned short b) {
  return __uint_as_float((unsigned)b << 16);
}
__device__ __forceinline__ float fexp2(float x) {
#if __has_builtin(__builtin_amdgcn_exp2f)
  return __builtin_amdgcn_exp2f(x);
#else
  return exp2f(x);
#endif
}
__device__ __forceinline__ f2v mk2(float a, float b) { f2v r; r[0] = a; r[1] = b; return r; }

// ---------------- prep bodies ----------------
__device__ __forceinline__ void gn_stats_body(
    int blk, const float* __restrict__ x, const float* __restrict__ gamma,
    const float* __restrict__ beta, float* __restrict__ ab, float* sh)
{
  int n = blk >> 5, g = blk & 31;
  int t = threadIdx.x; int cl = t >> 6, lane = t & 63;
  const float4* x4 = (const float4*)(x + (size_t)(n * 128 + g * 4 + cl) * 4096);
  float s = 0.f, ss = 0.f;
  #pragma unroll
  for (int j = 0; j < 16; ++j) {
    float4 v = x4[lane + 64 * j];
    s  += v.x + v.y + v.z + v.w;
    ss += v.x * v.x + v.y * v.y + v.z * v.z + v.w * v.w;
  }
  #pragma unroll
  for (int m = 32; m >= 1; m >>= 1) { s += __shfl_xor(s, m); ss += __shfl_xor(ss, m); }
  if (lane == 0) { sh[cl] = s; sh[4 + cl] = ss; }
  __syncthreads();
  if (t < 4) {
    float mu = (sh[0] + sh[1] + sh[2] + sh[3]) * (1.f / 16384.f);
    float e  = (sh[4] + sh[5] + sh[6] + sh[7]) * (1.f / 16384.f);
    float r  = rsqrtf(e - mu * mu + 1e-5f);
    int c = g * 4 + t;
    float al = gamma[c] * r;
    ab[n * 128 + c] = al;
    ab[1024 + n * 128 + c] = beta[c] - mu * al;
  }
}

__device__ __forceinline__ void pool_aff_body(
    int blk, const float* __restrict__ x,
    const float* __restrict__ g1, const float* __restrict__ b1,
    const float* __restrict__ g2, const float* __restrict__ b2,
    float* __restrict__ pooled, float* __restrict__ ab, float* sh)
{
  int n = blk >> 5, g = blk & 31;
  int t = threadIdx.x; int cl = t >> 6, lane = t & 63;
  int c = g * 4 + cl;
  const float* xb = x + (size_t)(n * 128 + c) * 4096;
  float* pb = pooled + (size_t)(n * 128 + c) * 1024;
  float s = 0.f, ss = 0.f;
  #pragma unroll
  for (int j = 0; j < 8; ++j) {
    int pp = (lane + 64 * j) * 2;
    int py = pp >> 5, px2 = pp & 31;
    const float* r0 = xb + py * 128 + px2 * 2;
    float4 A = *(const float4*)r0;
    float4 B = *(const float4*)(r0 + 64);
    float v0 = 0.25f * (A.x + A.y + B.x + B.y);
    float v1 = 0.25f * (A.z + A.w + B.z + B.w);
    float2 wv; wv.x = v0; wv.y = v1;
    *(float2*)(pb + pp) = wv;
    s += v0 + v1; ss += v0 * v0 + v1 * v1;
  }
  #pragma unroll
  for (int m = 32; m >= 1; m >>= 1) { s += __shfl_xor(s, m); ss += __shfl_xor(ss, m); }
  if (lane == 0) { sh[cl] = s; sh[4 + cl] = ss; }
  __syncthreads();
  if (t < 4) {
    float mu1 = (sh[0] + sh[1] + sh[2] + sh[3]) * (1.f / 4096.f);
    float e1  = (sh[4] + sh[5] + sh[6] + sh[7]) * (1.f / 4096.f);
    float r1  = rsqrtf(e1 - mu1 * mu1 + 1e-5f);
    float mzs = 0.f, e2s = 0.f;
    #pragma unroll
    for (int cc = 0; cc < 4; ++cc) {
      int ch = g * 4 + cc;
      float a = r1 * g1[ch];
      float d = b1[ch] - mu1 * a;
      float m = sh[cc] * (1.f / 1024.f);
      float q = sh[4 + cc] * (1.f / 1024.f);
      mzs += a * m + d;
      e2s += a * a * q + 2.f * a * d * m + d * d;
    }
    float mu2 = 0.25f * mzs;
    float r2  = rsqrtf(0.25f * e2s - mu2 * mu2 + 1e-5f);
    int ch = g * 4 + t;
    float a = r1 * g1[ch];
    float d = b1[ch] - mu1 * a;
    ab[n * 128 + ch] = a * r2 * g2[ch];
    ab[1024 + n * 128 + ch] = (d - mu2) * r2 * g2[ch] + b2[ch];
  }
}

__device__ __forceinline__ void wsplit_body(
    int b, const float* __restrict__ W, unsigned short* __restrict__ whi,
    unsigned short* __restrict__ wlo)
{
  int idx = b * 256 + threadIdx.x;
  #pragma unroll
  for (int k = 0; k < 4; ++k) {
    int f = idx + k * 4096;
    int o = f >> 7, c = f & 127;
    float v = W[f];
    unsigned short hb = f2bf(v);
    unsigned short lb = f2bf(v - bf2f(hb));
    int cq = c >> 2;
    int adr = (o * 16 + ((cq >> 1) ^ (o & 7))) * 8 + (cq & 1) * 4 + (c & 3);
    whi[adr] = hb; wlo[adr] = lb;
  }
}

__global__ __launch_bounds__(256) void prep_k(
    const float* __restrict__ q_src, const float* __restrict__ g_nq, const float* __restrict__ b_nq,
    const float* __restrict__ k_src, const float* __restrict__ g_srk, const float* __restrict__ b_srk,
    const float* __restrict__ g_nk, const float* __restrict__ b_nk,
    const float* __restrict__ v_src, const float* __restrict__ g_srv, const float* __restrict__ b_srv,
    const float* __restrict__ g_nv, const float* __restrict__ b_nv,
    const float* __restrict__ Wp,
    float* __restrict__ qab, float* __restrict__ kab, float* __restrict__ vab,
    float* __restrict__ knp, float* __restrict__ vnp,
    unsigned short* __restrict__ whi, unsigned short* __restrict__ wlo)
{
  __shared__ float sh[8];
  int b = blockIdx.x;
  if (b < 256) gn_stats_body(b, q_src, g_nq, b_nq, qab, sh);
  else if (b < 512) pool_aff_body(b - 256, k_src, g_srk, b_srk, g_nk, b_nk, knp, kab, sh);
  else if (b < 768) pool_aff_body(b - 512, v_src, g_srv, b_srv, g_nv, b_nv, vnp, vab, sh);
  else wsplit_body(b - 768, Wp, whi, wlo);
}

// ------- conv1x1 body with fused input affine (bf16 MFMA) -------
__device__ __forceinline__ void conv_body(
    int blk, const float* __restrict__ x, const float* __restrict__ ab,
    const float* __restrict__ W, const float* __restrict__ bias,
    unsigned short* __restrict__ po, int S, float outScale, int vt_mode,
    unsigned short* smem)
{
  unsigned short* Wsw = smem;
  unsigned short* xsw = smem + 16384;
  int t = threadIdx.x;
  int spb = S >> 7;
  int n  = blk / spb;
  int s0 = (blk % spb) << 7;

  #pragma unroll
  for (int k = 0; k < 16; ++k) {
    int f4 = t + (k << 8);
    int o = f4 >> 5, cq = f4 & 31;
    float4 wq = *(const float4*)(W + (size_t)o * 128 + cq * 4);
    union { unsigned q[2]; s4v v; } hv;
    asm("v_cvt_pk_bf16_f32 %0, %1, %2" : "=v"(hv.q[0]) : "v"(wq.x), "v"(wq.y));
    asm("v_cvt_pk_bf16_f32 %0, %1, %2" : "=v"(hv.q[1]) : "v"(wq.z), "v"(wq.w));
    *(s4v*)(Wsw + (o * 16 + ((cq >> 1) ^ (o & 7))) * 8 + (cq & 1) * 4) = hv.v;
  }
  int sl = t & 127, coh = t >> 7;
  for (int co = coh; co < 16; co += 2) {
    const float* xb = x + (size_t)(n * 128 + co * 8) * S + s0 + sl;
    const float* aa = ab + n * 128 + co * 8;
    const float* bb = aa + 1024;
    float f[8];
    #pragma unroll
    for (int e = 0; e < 8; ++e) f[e] = fmaf(xb[(size_t)e * S], aa[e], bb[e]);
    union { unsigned q[4]; s8v v; } xv;
    #pragma unroll
    for (int e = 0; e < 4; ++e)
      asm("v_cvt_pk_bf16_f32 %0, %1, %2" : "=v"(xv.q[e]) : "v"(f[2*e]), "v"(f[2*e+1]));
    *(s8v*)(xsw + (co * 128 + sl) * 8) = xv.v;
  }
  __syncthreads();

  int lane = t & 63, w = t >> 6;
  int l31 = lane & 31, h = lane >> 5;
  int wo = (w & 1) << 6, wsp = (w >> 1) << 6;
  f16v acc00 = {}, acc01 = {}, acc10 = {}, acc11 = {};
  #pragma unroll
  for (int reg = 0; reg < 16; ++reg) {
    int rm = (reg & 3) + ((reg >> 2) << 3) + (h << 2);
    float b0 = bias[wo + rm], b1 = bias[wo + 32 + rm];
    acc00[reg] = b0; acc01[reg] = b0; acc10[reg] = b1; acc11[reg] = b1;
  }
  const s8v* Wv = (const s8v*)Wsw;
  const s8v* Xv = (const s8v*)xsw;
  int o0 = wo + l31, o1 = wo + 32 + l31;
  #pragma unroll
  for (int cs = 0; cs < 8; ++cs) {
    int kk = cs * 2 + h;
    s8v a0 = Wv[o0 * 16 + (kk ^ (o0 & 7))];
    s8v a1 = Wv[o1 * 16 + (kk ^ (o1 & 7))];
    s8v b0 = Xv[kk * 128 + wsp + l31];
    s8v b1 = Xv[kk * 128 + wsp + 32 + l31];
    acc00 = __builtin_amdgcn_mfma_f32_32x32x16_bf16(a0, b0, acc00, 0, 0, 0);
    acc01 = __builtin_amdgcn_mfma_f32_32x32x16_bf16(a0, b1, acc01, 0, 0, 0);
    acc10 = __builtin_amdgcn_mfma_f32_32x32x16_bf16(a1, b0, acc10, 0, 0, 0);
    acc11 = __builtin_amdgcn_mfma_f32_32x32x16_bf16(a1, b1, acc11, 0, 0, 0);
  }
  __syncthreads();
  unsigned short* ot = smem; // [128][132]
  #pragma unroll
  for (int reg = 0; reg < 16; ++reg) {
    int rm = (reg & 3) + ((reg >> 2) << 3) + (h << 2);
    ot[(wo + rm) * 132 + wsp + l31]           = f2bf(acc00[reg] * outScale);
    ot[(wo + rm) * 132 + wsp + 32 + l31]      = f2bf(acc01[reg] * outScale);
    ot[(wo + 32 + rm) * 132 + wsp + l31]      = f2bf(acc10[reg] * outScale);
    ot[(wo + 32 + rm) * 132 + wsp + 32 + l31] = f2bf(acc11[reg] * outScale);
  }
  __syncthreads();
  if (!vt_mode) {
    unsigned* po32 = (unsigned*)po;
    int d2 = t & 15;
    for (int i = 0; i < 32; ++i) {
      int pr = (t >> 4) + (i << 4);
      int s = pr & 127, ohi_ = pr >> 7;
      unsigned lo = ot[(ohi_ * 32 + d2 * 2) * 132 + s];
      unsigned hi = ot[(ohi_ * 32 + d2 * 2 + 1) * 132 + s];
      po32[((size_t)(n * 4 + ohi_) * S + s0 + s) * 16 + d2] = lo | (hi << 16);
    }
  } else {
    unsigned* po32 = (unsigned*)po;
    const unsigned* ot32 = (const unsigned*)ot; // [128][66]
    int sp = t & 63;
    for (int i = 0; i < 32; ++i) {
      int rr = (t >> 6) + (i << 2);
      po32[((size_t)(n * 4 + (rr >> 5)) * 32 + (rr & 31)) * (S >> 1) + (s0 >> 1) + sp] =
          ot32[rr * 66 + sp];
    }
  }
}

__global__ __launch_bounds__(256) void convs_k(
    const float* __restrict__ q_src, const float* __restrict__ qab,
    const float* __restrict__ Wq, const float* __restrict__ bq, unsigned short* __restrict__ qhb,
    const float* __restrict__ knp, const float* __restrict__ kab,
    const float* __restrict__ Wk, const float* __restrict__ bk, unsigned short* __restrict__ khb,
    const float* __restrict__ vnp, const float* __restrict__ vab,
    const float* __restrict__ Wv, const float* __restrict__ bv, unsigned short* __restrict__ vtb,
    float qscale)
{
  __shared__ __align__(16) unsigned short smem[32768];
  int b = blockIdx.x;
  if (b < 256)      conv_body(b,       q_src, qab, Wq, bq, qhb, 4096, qscale, 0, smem);
  else if (b < 320) conv_body(b - 256, knp,   kab, Wk, bk, khb, 1024, 1.0f,   0, smem);
  else              conv_body(b - 320, vnp,   vab, Wv, bv, vtb, 1024, 1.0f,   1, smem);
}

// ------- fused attention + projection (R17 best + hoisted tile fragment loads) -------
// Block = (n, qb: 128 q-rows). 1024 threads = 16 waves: wave (hh = w&3, qr = w>>2).
// XCD x owns image n=x (256 = 8 XCDs x 32 chunked blocks) -> KV L2-resident.
// qh: [N*4][4096][32] bf16 (pre-scaled). kh: [N*4][1024][32]. vt: [N*4][32][1024].
// whi/wlo: Wp frag images. out: [N][128][4096] f32.
__global__ __launch_bounds__(1024) void attn_proj_k(
    const unsigned short* __restrict__ qh, const unsigned short* __restrict__ kh,
    const unsigned short* __restrict__ vt, const unsigned short* __restrict__ whi,
    const unsigned short* __restrict__ wlo, const float* __restrict__ bp,
    float* __restrict__ out)
{
  __shared__ __align__(16) unsigned char SM[67584]; // 64KB KV (aliased X) + 2KB linv
  unsigned short* S16 = (unsigned short*)SM;
  float* linvp = (float*)(SM + 65536);
  int t = threadIdx.x;
  int lane = t & 63, w = t >> 6;
  int l31 = lane & 31, h = lane >> 5;
  int hh = w & 3, qr = w >> 2;
  int b0 = blockIdx.x;
  int blk = (b0 & 7) * 32 + (b0 >> 3);   // bijective XCD chunking (256 = 8*32)
  int n = blk >> 5, qb = blk & 31;

  const unsigned short* qp =
      qh + (((size_t)(n * 4 + hh) * 4096 + qb * 128 + qr * 32 + l31) << 5);
  s8v qf0 = *(const s8v*)(qp + h * 8);
  s8v qf1 = *(const s8v*)(qp + (2 + h) * 8);

  // per-head staging: thread t -> head sh_=t>>8, unit si=t&255
  int sh_ = t >> 8, si = t & 255;
  size_t kvb = (size_t)(n * 4 + sh_) << 15;
  const unsigned short* kg = kh + kvb + ((si >> 2) << 5) + ((si & 3) << 3);
  const unsigned short* vg = vt + kvb + ((size_t)(si >> 3) << 10) + ((si & 7) << 3);
  int ku = (si & ~3) | ((si & 3) ^ ((si >> 3) & 3));
  int vu = (si & ~7) | ((si & 7) ^ ((si >> 3) & 7));

  // prologue: tile 0 -> buf 0
  s8v rk = *(const s8v*)kg;
  s8v rvv = *(const s8v*)vg;
  *(s8v*)(S16 + sh_ * 2048 + ku * 8) = rk;
  *(s8v*)(S16 + 16384 + sh_ * 2048 + vu * 8) = rvv;

  const f16v fz = {};
  f16v oacc = fz;
  f2v lp0 = mk2(0.f, 0.f), lp1 = mk2(0.f, 0.f);
  int kx = (l31 >> 1) & 3;
  int vx = l31 & 7;
  int krow = l31 * 4;

  for (int tile = 0; tile < 16; ++tile) {
    int buf = tile & 1;
    __syncthreads();
    if (tile < 15) {
      int j = (tile + 1) << 6;
      rk = *(const s8v*)(kg + (size_t)j * 32);
      rvv = *(const s8v*)(vg + j);
    }
    const unsigned short* Kb = S16 + (buf * 4 + hh) * 2048;
    const unsigned short* Vb = S16 + 16384 + (buf * 4 + hh) * 2048;

    // hoisted fragment loads for BOTH sub-steps (pipeline all 8 ds_reads before setprio)
    s8v kfa0 = *(const s8v*)(Kb + ((krow + (h ^ kx)) << 3));
    s8v kfa1 = *(const s8v*)(Kb + ((krow + ((2 + h) ^ kx)) << 3));
    s8v kfb0 = *(const s8v*)(Kb + ((128 + krow + (h ^ kx)) << 3));
    s8v kfb1 = *(const s8v*)(Kb + ((128 + krow + ((2 + h) ^ kx)) << 3));
    s8v vfa0 = *(const s8v*)(Vb + ((l31 * 8 + (h ^ vx)) << 3));
    s8v vfa1 = *(const s8v*)(Vb + ((l31 * 8 + ((2 + h) ^ vx)) << 3));
    s8v vfb0 = *(const s8v*)(Vb + ((l31 * 8 + ((4 + h) ^ vx)) << 3));
    s8v vfb1 = *(const s8v*)(Vb + ((l31 * 8 + ((6 + h) ^ vx)) << 3));

    // ---- sub-step 0 ----
    {
      __builtin_amdgcn_s_setprio(1);
      f16v sf = __builtin_amdgcn_mfma_f32_32x32x16_bf16(kfa0, qf0, fz, 0, 0, 0);
      sf = __builtin_amdgcn_mfma_f32_32x32x16_bf16(kfa1, qf1, sf, 0, 0, 0);
      __builtin_amdgcn_s_setprio(0);
      float p[16];
      #pragma unroll
      for (int r = 0; r < 16; ++r) p[r] = fexp2(sf[r]);
      lp0 += mk2(p[0], p[1]);  lp1 += mk2(p[2], p[3]);
      lp0 += mk2(p[4], p[5]);  lp1 += mk2(p[6], p[7]);
      lp0 += mk2(p[8], p[9]);  lp1 += mk2(p[10], p[11]);
      lp0 += mk2(p[12], p[13]); lp1 += mk2(p[14], p[15]);
      unsigned c[8];
      #pragma unroll
      for (int q = 0; q < 8; ++q)
        asm("v_cvt_pk_bf16_f32 %0, %1, %2" : "=v"(c[q]) : "v"(p[2 * q]), "v"(p[2 * q + 1]));
      i2v s02 = __builtin_amdgcn_permlane32_swap((int)c[0], (int)c[2], false, false);
      i2v s13 = __builtin_amdgcn_permlane32_swap((int)c[1], (int)c[3], false, false);
      i2v s46 = __builtin_amdgcn_permlane32_swap((int)c[4], (int)c[6], false, false);
      i2v s57 = __builtin_amdgcn_permlane32_swap((int)c[5], (int)c[7], false, false);
      union { int u[4]; s8v v; } u0, u1;
      u0.u[0] = s02[0]; u0.u[1] = s13[0]; u0.u[2] = s02[1]; u0.u[3] = s13[1];
      u1.u[0] = s46[0]; u1.u[1] = s57[0]; u1.u[2] = s46[1]; u1.u[3] = s57[1];
      __builtin_amdgcn_s_setprio(1);
      oacc = __builtin_amdgcn_mfma_f32_32x32x16_bf16(u0.v, vfa0, oacc, 0, 0, 0);
      oacc = __builtin_amdgcn_mfma_f32_32x32x16_bf16(u1.v, vfa1, oacc, 0, 0, 0);
      __builtin_amdgcn_s_setprio(0);
    }
    // ---- sub-step 1 ----
    {
      __builtin_amdgcn_s_setprio(1);
      f16v sf = __builtin_amdgcn_mfma_f32_32x32x16_bf16(kfb0, qf0, fz, 0, 0, 0);
      sf = __builtin_amdgcn_mfma_f32_32x32x16_bf16(kfb1, qf1, sf, 0, 0, 0);
      __builtin_amdgcn_s_setprio(0);
      float p[16];
      #pragma unroll
      for (int r = 0; r < 16; ++r) p[r] = fexp2(sf[r]);
      lp0 += mk2(p[0], p[1]);  lp1 += mk2(p[2], p[3]);
      lp0 += mk2(p[4], p[5]);  lp1 += mk2(p[6], p[7]);
      lp0 += mk2(p[8], p[9]);  lp1 += mk2(p[10], p[11]);
      lp0 += mk2(p[12], p[13]); lp1 += mk2(p[14], p[15]);
      unsigned c[8];
      #pragma unroll
      for (int q = 0; q < 8; ++q)
        asm("v_cvt_pk_bf16_f32 %0, %1, %2" : "=v"(c[q]) : "v"(p[2 * q]), "v"(p[2 * q + 1]));
      i2v s02 = __builtin_amdgcn_permlane32_swap((int)c[0], (int)c[2], false, false);
      i2v s13 = __builtin_amdgcn_permlane32_swap((int)c[1], (int)c[3], false, false);
      i2v s46 = __builtin_amdgcn_permlane32_swap((int)c[4], (int)c[6], false, false);
      i2v s57 = __builtin_amdgcn_permlane32_swap((int)c[5], (int)c[7], false, false);
      union { int u[4]; s8v v; } u0, u1;
      u0.u[0] = s02[0]; u0.u[1] = s13[0]; u0.u[2] = s02[1]; u0.u[3] = s13[1];
      u1.u[0] = s46[0]; u1.u[1] = s57[0]; u1.u[2] = s46[1]; u1.u[3] = s57[1];
      __builtin_amdgcn_s_setprio(1);
      oacc = __builtin_amdgcn_mfma_f32_32x32x16_bf16(u0.v, vfb0, oacc, 0, 0, 0);
      oacc = __builtin_amdgcn_mfma_f32_32x32x16_bf16(u1.v, vfb1, oacc, 0, 0, 0);
      __builtin_amdgcn_s_setprio(0);
    }
    if (tile < 15) {
      *(s8v*)(S16 + ((buf ^ 1) * 4 + sh_) * 2048 + ku * 8) = rk;
      *(s8v*)(S16 + 16384 + ((buf ^ 1) * 4 + sh_) * 2048 + vu * 8) = rvv;
    }
  }

  // softmax denominators -> linv[head][row]
  float l_part = lp0[0] + lp0[1] + lp1[0] + lp1[1];
  float l_tot = l_part + __shfl_xor(l_part, 32);
  if (h == 0) linvp[hh * 128 + qr * 32 + l31] = 1.0f / l_tot;
  __syncthreads();  // KV reads done; linv visible; safe to alias KV region as X

  // write normalized O (hi/lo bf16) into LDS as conv B layout [ch-oct][row], XOR row^co
  unsigned short* Xh16 = S16;
  unsigned short* Xl16 = S16 + 16384;
  int ch = hh * 32 + l31, co = ch >> 3, el = ch & 7;
  #pragma unroll
  for (int reg = 0; reg < 16; ++reg) {
    int rm = (reg & 3) + ((reg >> 2) << 3) + (h << 2);
    int row = qr * 32 + rm;
    float val = oacc[reg] * linvp[hh * 128 + row];
    unsigned short hb = f2bf(val);
    unsigned short lb = f2bf(val - bf2f(hb));
    int xu = co * 128 + (row ^ co);
    Xh16[xu * 8 + el] = hb;
    Xl16[xu * 8 + el] = lb;
  }
  __syncthreads();

  // projection: wave (hh,qr) -> out channels [hh*32,+32) x spatial rows [qr*32,+32)
  int ol = hh * 32 + l31;
  const s8v* WH = (const s8v*)whi;
  const s8v* WL = (const s8v*)wlo;
  s8v ah[8], al[8];
  #pragma unroll
  for (int cs = 0; cs < 8; ++cs) {
    int kk = cs * 2 + h;
    int ia = ol * 16 + (kk ^ (ol & 7));
    ah[cs] = WH[ia];
    al[cs] = WL[ia];
  }
  f16v acc;
  #pragma unroll
  for (int reg = 0; reg < 16; ++reg) {
    int rm = (reg & 3) + ((reg >> 2) << 3) + (h << 2);
    acc[reg] = bp[hh * 32 + rm];
  }
  int srow = qr * 32 + l31;
  #pragma unroll
  for (int cs = 0; cs < 8; ++cs) {
    int kk = cs * 2 + h;
    int xu = kk * 128 + (srow ^ kk);
    s8v bh = *(const s8v*)(Xh16 + xu * 8);
    s8v bl = *(const s8v*)(Xl16 + xu * 8);
    acc = __builtin_amdgcn_mfma_f32_32x32x16_bf16(ah[cs], bh, acc, 0, 0, 0);
    acc = __builtin_amdgcn_mfma_f32_32x32x16_bf16(ah[cs], bl, acc, 0, 0, 0);
    acc = __builtin_amdgcn_mfma_f32_32x32x16_bf16(al[cs], bh, acc, 0, 0, 0);
  }
  #pragma unroll
  for (int reg = 0; reg < 16; ++reg) {
    int rm = (reg & 3) + ((reg >> 2) << 3) + (h << 2);
    out[(size_t)(n * 128 + hh * 32 + rm) * 4096 + qb * 128 + srow] = acc[reg];
  }
}

extern "C" void kernel_launch(void* const* d_in, const int* in_sizes, int n_in,
                              void* d_out, int out_size, void* d_ws, size_t ws_size,
                              hipStream_t stream)
{
  (void)in_sizes; (void)n_in; (void)out_size; (void)ws_size;
  const float* q_src = (const float*)d_in[0];
  const float* k_src = (const float*)d_in[1];
  const float* v_src = (const float*)d_in[2];
  const float* Wq = (const float*)d_in[3];
  const float* bq = (const float*)d_in[4];
  const float* Wk = (const float*)d_in[5];
  const float* bk = (const float*)d_in[6];
  const float* Wv = (const float*)d_in[7];
  const float* bv = (const float*)d_in[8];
  const float* Wp = (const float*)d_in[9];
  const float* bp = (const float*)d_in[10];
  const float* g_nq  = (const float*)d_in[11];
  const float* b_nq  = (const float*)d_in[12];
  const float* g_nk  = (const float*)d_in[13];
  const float* b_nk  = (const float*)d_in[14];
  const float* g_nv  = (const float*)d_in[15];
  const float* b_nv  = (const float*)d_in[16];
  const float* g_srk = (const float*)d_in[17];
  const float* b_srk = (const float*)d_in[18];
  const float* g_srv = (const float*)d_in[19];
  const float* b_srv = (const float*)d_in[20];

  unsigned short* qhb = (unsigned short*)d_ws;            // 8MB
  unsigned short* khb = qhb + 4194304;                    // 2MB
  unsigned short* vtb = khb + 1048576;                    // 2MB
  float* knp  = (float*)(vtb + 1048576);                  // 4MB
  float* vnp  = knp + 1048576;                            // 4MB
  float* qab  = vnp + 1048576;                            // 8KB
  float* kab  = qab + 2048;
  float* vab  = kab + 2048;
  unsigned short* whi = (unsigned short*)(vab + 2048);    // 32KB
  unsigned short* wlo = whi + 16384;

  const float QSCALE = 0.17677669529663688f * 1.44269504088896340f;

  prep_k<<<784, 256, 0, stream>>>(q_src, g_nq, b_nq,
                                  k_src, g_srk, b_srk, g_nk, b_nk,
                                  v_src, g_srv, b_srv, g_nv, b_nv,
                                  Wp, qab, kab, vab, knp, vnp, whi, wlo);
  convs_k<<<384, 256, 0, stream>>>(q_src, qab, Wq, bq, qhb,
                                   knp, kab, Wk, bk, khb,
                                   vnp, vab, Wv, bv, vtb, QSCALE);
  attn_proj_k<<<256, 1024, 0, stream>>>(qhb, khb, vtb, whi, wlo, bp, (float*)d_out);
}